// Round 8
// baseline (180.421 us; speedup 1.0000x reference)
//
#include <hip/hip_runtime.h>
#include <hip/hip_bf16.h>

#define NROWS 8192
#define DIM 512
#define BM 256
#define BN 256

typedef __bf16 bf16x8 __attribute__((ext_vector_type(8)));
typedef unsigned short u16x8 __attribute__((ext_vector_type(8)));
typedef float f32x4 __attribute__((ext_vector_type(4)));

__device__ __forceinline__ unsigned short f2bf(float f) {
  unsigned int u = __float_as_uint(f);
  u += 0x7fffu + ((u >> 16) & 1u);
  return (unsigned short)(u >> 16);
}

__device__ __forceinline__ void gld_lds16(const void* g, void* l) {
  __builtin_amdgcn_global_load_lds(
      (__attribute__((address_space(1))) unsigned int*)(g),
      (__attribute__((address_space(3))) unsigned int*)(l),
      16, 0, 0);
}

// ---------- Phase 1: normalize rows -> bf16; diag logits in fp32 ----------
__global__ __launch_bounds__(128) void prep_k(
    const float* __restrict__ q, const float* __restrict__ p,
    unsigned short* __restrict__ qh, unsigned short* __restrict__ ph,
    float* __restrict__ diag) {
  const int i = blockIdx.x;
  const int t = threadIdx.x;
  const int lane = t & 63, wid = t >> 6;
  const float4 qv = ((const float4*)(q + (size_t)i * DIM))[t];
  const float4 pv = ((const float4*)(p + (size_t)i * DIM))[t];
  float ssq = qv.x*qv.x + qv.y*qv.y + qv.z*qv.z + qv.w*qv.w;
  float ssp = pv.x*pv.x + pv.y*pv.y + pv.z*pv.z + pv.w*pv.w;
  float dt  = qv.x*pv.x + qv.y*pv.y + qv.z*pv.z + qv.w*pv.w;
  #pragma unroll
  for (int m = 1; m < 64; m <<= 1) {
    ssq += __shfl_xor(ssq, m, 64);
    ssp += __shfl_xor(ssp, m, 64);
    dt  += __shfl_xor(dt,  m, 64);
  }
  __shared__ float red[3][2];
  if (lane == 0) { red[0][wid] = ssq; red[1][wid] = ssp; red[2][wid] = dt; }
  __syncthreads();
  ssq = red[0][0] + red[0][1];
  ssp = red[1][0] + red[1][1];
  dt  = red[2][0] + red[2][1];
  const float invq = 1.0f / fmaxf(sqrtf(ssq), 1e-8f);
  const float invp = 1.0f / fmaxf(sqrtf(ssp), 1e-8f);
  ushort4 qo, po;
  qo.x = f2bf(qv.x * invq); qo.y = f2bf(qv.y * invq);
  qo.z = f2bf(qv.z * invq); qo.w = f2bf(qv.w * invq);
  po.x = f2bf(pv.x * invp); po.y = f2bf(pv.y * invp);
  po.z = f2bf(pv.z * invp); po.w = f2bf(pv.w * invp);
  ((ushort4*)(qh + (size_t)i * DIM))[t] = qo;
  ((ushort4*)(ph + (size_t)i * DIM))[t] = po;
  if (t == 0) diag[i] = dt * invq * invp * 20.0f;
}

// ---------- Phase 2: persistent GEMM, cross-tile modulo schedule ----------
// 256 blocks (1/CU), 8 waves (2Mx4N), 128x64 out/wave, 4 output tiles/block.
// Tile t's 24 ds_read_b128 issue during tile t-1's Q11/Q10 MFMA shadow and
// land in registers vacated by the consuming quadrant (af0 dead after Q01,
// bf1 after Q11, bf0/af1 after Q10) -> LDS pipe runs under the matrix pipe.
// Counted-lgkm invariants (in-order retirement):
//   issue order per tile tail: af0'(8), bf1'(4), bf0'(4), [sched_bar] af1'(8)
//   Q00 waits lgkm(8)  -> af0,bf1,bf0 done (af1 may be in flight)
//   Q11 waits lgkm(8)  -> af1 done (only af0' younger); t=31: lgkm(0)
// One vmcnt(0)+barrier per tile publishes the next buffer (stages issued a
// full tile earlier). Stage(t+2) targets this tile's read buffer, issued
// after B_t, i.e. after all its reads are lgkm-complete.
__device__ __forceinline__ void read_af(bf16x8 af[2][4], const char* rb,
                                        int qm, int rowAoff, int l4swz) {
  #pragma unroll
  for (int ks = 0; ks < 2; ++ks)
    #pragma unroll
    for (int mf = 0; mf < 4; ++mf)
      af[ks][mf] = __builtin_bit_cast(bf16x8,
          *(const u16x8*)(rb + qm * 16384 + rowAoff + mf * 2048 + (l4swz ^ (ks * 64))));
}
__device__ __forceinline__ void read_bf(bf16x8 bfr[2][2], const char* rb,
                                        int qn, int rowBoff, int l4swz) {
  #pragma unroll
  for (int ks = 0; ks < 2; ++ks)
    #pragma unroll
    for (int nf = 0; nf < 2; ++nf)
      bfr[ks][nf] = __builtin_bit_cast(bf16x8,
          *(const u16x8*)(rb + 32768 + qn * 16384 + rowBoff + nf * 2048 + (l4swz ^ (ks * 64))));
}
__device__ __forceinline__ void stage_half(const char* __restrict__ g, char* dstb,
                                           int rowbase, int h, int tid, int kb) {
  #pragma unroll
  for (int j = 0; j < 2; ++j) {
    const int idx = j * 512 + tid;
    const int rl = idx >> 3;
    const int scb = ((idx & 7) << 4) ^ ((rl & 7) << 4);
    gld_lds16(g + (size_t)(rowbase + h * 128 + rl) * 1024 + kb + scb,
              dstb + h * 16384 + idx * 16);
  }
}

#define MFMA_Q(AF, BF, QM, QN)                                                \
  __builtin_amdgcn_s_setprio(1);                                              \
  _Pragma("unroll") for (int mf = 0; mf < 4; ++mf)                            \
    _Pragma("unroll") for (int nf = 0; nf < 2; ++nf)                          \
      _Pragma("unroll") for (int ks = 0; ks < 2; ++ks)                        \
        acc[QM * 4 + mf][QN * 2 + nf] =                                       \
            __builtin_amdgcn_mfma_f32_16x16x32_bf16(                          \
                AF[ks][mf], BF[ks][nf], acc[QM * 4 + mf][QN * 2 + nf], 0, 0, 0); \
  __builtin_amdgcn_s_setprio(0);

#define LGKM8()                                                               \
  asm volatile("s_waitcnt lgkmcnt(8)" ::: "memory");                          \
  __builtin_amdgcn_sched_barrier(0);

#define LGKM0()                                                               \
  asm volatile("s_waitcnt lgkmcnt(0)" ::: "memory");                          \
  __builtin_amdgcn_sched_barrier(0);

__global__ __launch_bounds__(512, 2) void gemm_lse_k(
    const unsigned short* __restrict__ qh, const unsigned short* __restrict__ ph,
    float* __restrict__ partial) {
  __shared__ __attribute__((aligned(16))) char lds[135168];  // 2x64KB + 4KB psum
  const int tid = threadIdx.x;
  const int lane = tid & 63, wid = tid >> 6;
  const int wr = wid >> 2, wc = wid & 3;
  const int l15 = lane & 15, l4 = lane >> 4;
  const int rowAoff = (wr * 64 + l15) * 128;
  const int rowBoff = (wc * 32 + l15) * 128;
  const int l4swz = (l4 << 4) ^ ((l15 & 7) << 4);
  const int b = blockIdx.x;
  const int bxg = b & 7;            // XCD id -> B column group
  const int by = b >> 3;            // 0..31
  const int bm = by * BM;
  const char* qh8 = (const char*)qh;
  const char* ph8 = (const char*)ph;
  float* psum = (float*)(lds + 131072);

  f32x4 acc[8][4] = {};
  bf16x8 af0[2][4], af1[2][4], bf0[2][2], bf1[2][2];

  // ---- Prologue: stage tile0 -> buf0; read its 24 frags; stage tile1 ----
  {
    const int bn0 = bxg * 4 * BN;
    stage_half(qh8, lds, bm, 0, tid, 0);
    stage_half(ph8, lds + 32768, bn0, 0, tid, 0);
    stage_half(ph8, lds + 32768, bn0, 1, tid, 0);
    stage_half(qh8, lds, bm, 1, tid, 0);
    asm volatile("s_waitcnt vmcnt(0)" ::: "memory");
    __builtin_amdgcn_s_barrier();
    read_af(af0, lds, 0, rowAoff, l4swz);
    read_bf(bf1, lds, 1, rowBoff, l4swz);
    read_bf(bf0, lds, 0, rowBoff, l4swz);
    __builtin_amdgcn_sched_barrier(0);     // pin: af1 reads are youngest 8
    read_af(af1, lds, 1, rowAoff, l4swz);
    stage_half(qh8, lds + 65536, bm, 0, tid, 128);
    stage_half(ph8, lds + 65536 + 32768, bn0, 0, tid, 128);
    stage_half(ph8, lds + 65536 + 32768, bn0, 1, tid, 128);
    stage_half(qh8, lds + 65536, bm, 1, tid, 128);
  }

  #pragma unroll 1
  for (int tt = 0; tt < 32; ++tt) {
    const char* rbn = lds + ((tt + 1) & 1) * 65536;  // next tile's buffer
    char* sb2 = lds + (tt & 1) * 65536;              // stage target (tt+2)
    const int kb2 = ((tt + 2) & 7) * 128;
    const int bn2 = (bxg * 4 + (((tt + 2) & 31) >> 3)) * BN;

    LGKM8();                       // af0,bf1,bf0 of tile tt landed
    MFMA_Q(af0, bf0, 0, 0);
    MFMA_Q(af0, bf1, 0, 1);

    asm volatile("s_waitcnt vmcnt(0)" ::: "memory");  // stage(tt+1) landed
    __builtin_amdgcn_s_barrier();                     // B_t: publish rbn

    if (tt < 31) read_af(af0, rbn, 0, rowAoff, l4swz);   // af0' (8)
    if (tt < 31) { LGKM8(); }      // af1(tt) done (only af0' younger)
    else         { LGKM0(); }
    MFMA_Q(af1, bf1, 1, 1);
    if (tt < 31) read_bf(bf1, rbn, 1, rowBoff, l4swz);   // bf1' (4)
    if (tt < 30) {
      stage_half(qh8, sb2, bm, 0, tid, kb2);             // A0(tt+2)
      stage_half(ph8, sb2 + 32768, bn2, 0, tid, kb2);    // B0(tt+2)
    }
    MFMA_Q(af1, bf0, 1, 0);
    if (tt < 31) {
      read_bf(bf0, rbn, 0, rowBoff, l4swz);              // bf0' (4)
      __builtin_amdgcn_sched_barrier(0);                 // pin bf0' < af1'
      read_af(af1, rbn, 1, rowAoff, l4swz);              // af1' (8)
    }
    if (tt < 30) {
      stage_half(ph8, sb2 + 32768, bn2, 1, tid, kb2);    // B1(tt+2)
      stage_half(qh8, sb2, bm, 1, tid, kb2);             // A1(tt+2)
    }

    if ((tt & 7) == 7) {
      // ---- flush output tile (tt>>3): exp + row-sum + store ----
      const int bxc = bxg * 4 + (tt >> 3);
      #pragma unroll
      for (int am = 0; am < 8; ++am) {
        #pragma unroll
        for (int r = 0; r < 4; ++r) {
          float s = 0.0f;
          #pragma unroll
          for (int nb = 0; nb < 4; ++nb)
            s += __expf(acc[am][nb][r] * 20.0f - 20.0f);
          s += __shfl_xor(s, 1, 64);
          s += __shfl_xor(s, 2, 64);
          s += __shfl_xor(s, 4, 64);
          s += __shfl_xor(s, 8, 64);
          if (l15 == 0)
            psum[wc * 256 + (am >> 2) * 128 + wr * 64 + (am & 3) * 16 + l4 * 4 + r] = s;
        }
      }
      asm volatile("s_waitcnt lgkmcnt(0)" ::: "memory");
      __builtin_amdgcn_s_barrier();
      if (tid < 256) {
        float s = psum[tid] + psum[256 + tid] + psum[512 + tid] + psum[768 + tid];
        partial[(size_t)(bm + tid) * 32 + bxc] = s;
      }
      #pragma unroll
      for (int am = 0; am < 8; ++am)
        #pragma unroll
        for (int nb = 0; nb < 4; ++nb)
          acc[am][nb] = f32x4{0.0f, 0.0f, 0.0f, 0.0f};
    }
  }
}

// ---------- Phase 3a: per-row loss ----------
__global__ __launch_bounds__(256) void rowloss_k(
    const float* __restrict__ partial, const float* __restrict__ diag,
    float* __restrict__ rowloss) {
  const int i = blockIdx.x * 256 + threadIdx.x;
  const float4* pr = (const float4*)(partial + (size_t)i * 32);
  float s = 0.0f;
  #pragma unroll
  for (int c = 0; c < 8; ++c) {
    const float4 v = pr[c];
    s += v.x + v.y + v.z + v.w;
  }
  rowloss[i] = __logf(s) + 20.0f - diag[i];
}

// ---------- Phase 3b: mean ----------
__global__ __launch_bounds__(1024) void final_k(
    const float* __restrict__ rowloss, float* __restrict__ out) {
  const int t = threadIdx.x;
  float s = 0.0f;
  #pragma unroll
  for (int j = 0; j < 8; ++j) s += rowloss[t + j * 1024];
  #pragma unroll
  for (int m = 1; m < 64; m <<= 1) s += __shfl_xor(s, m, 64);
  __shared__ float red[16];
  if ((t & 63) == 0) red[t >> 6] = s;
  __syncthreads();
  if (t == 0) {
    float acc = 0.0f;
    #pragma unroll
    for (int w = 0; w < 16; ++w) acc += red[w];
    out[0] = acc * (1.0f / (float)NROWS);
  }
}

extern "C" void kernel_launch(void* const* d_in, const int* in_sizes, int n_in,
                              void* d_out, int out_size, void* d_ws, size_t ws_size,
                              hipStream_t stream) {
  const float* q = (const float*)d_in[0];
  const float* p = (const float*)d_in[1];
  char* w = (char*)d_ws;
  unsigned short* qh = (unsigned short*)w;                    // 8 MB
  unsigned short* ph = (unsigned short*)(w + 8388608);        // 8 MB
  float* partial    = (float*)(w + 16777216);                 // 1 MB [8192][32]
  float* diag       = (float*)(w + 17825792);                 // 32 KB
  float* rowloss    = (float*)(w + 17858560);                 // 32 KB
  float* out = (float*)d_out;

  prep_k<<<NROWS, 128, 0, stream>>>(q, p, qh, ph, diag);
  gemm_lse_k<<<256, 512, 0, stream>>>(qh, ph, partial);
  rowloss_k<<<NROWS / 256, 256, 0, stream>>>(partial, diag, rowloss);
  final_k<<<1, 1024, 0, stream>>>(rowloss, out);
}

// Round 9
// 75.652 us; speedup vs baseline: 2.3849x; 2.3849x over previous
//
#include <hip/hip_runtime.h>
#include <hip/hip_bf16.h>

#define NROWS 8192
#define DIM 512
#define BM 256
#define BN 256

typedef int   i32x4 __attribute__((ext_vector_type(4)));
typedef int   i32x8 __attribute__((ext_vector_type(8)));
typedef float f32x4 __attribute__((ext_vector_type(4)));

#define FP8_SCALE_1 0x7f7f7f7f   // E8M0 127 = 2^0 in all 4 bytes

__device__ __forceinline__ void gld_lds16(const void* g, void* l) {
  __builtin_amdgcn_global_load_lds(
      (__attribute__((address_space(1))) unsigned int*)(g),
      (__attribute__((address_space(3))) unsigned int*)(l),
      16, 0, 0);
}

// ---------- Phase 1: normalize rows -> fp8 e4m3; diag logits in fp32 ----------
__global__ __launch_bounds__(128) void prep_k(
    const float* __restrict__ q, const float* __restrict__ p,
    unsigned int* __restrict__ qh, unsigned int* __restrict__ ph,
    float* __restrict__ diag) {
  const int i = blockIdx.x;
  const int t = threadIdx.x;
  const int lane = t & 63, wid = t >> 6;
  const float4 qv = ((const float4*)(q + (size_t)i * DIM))[t];
  const float4 pv = ((const float4*)(p + (size_t)i * DIM))[t];
  float ssq = qv.x*qv.x + qv.y*qv.y + qv.z*qv.z + qv.w*qv.w;
  float ssp = pv.x*pv.x + pv.y*pv.y + pv.z*pv.z + pv.w*pv.w;
  float dt  = qv.x*pv.x + qv.y*pv.y + qv.z*pv.z + qv.w*pv.w;
  #pragma unroll
  for (int m = 1; m < 64; m <<= 1) {
    ssq += __shfl_xor(ssq, m, 64);
    ssp += __shfl_xor(ssp, m, 64);
    dt  += __shfl_xor(dt,  m, 64);
  }
  __shared__ float red[3][2];
  if (lane == 0) { red[0][wid] = ssq; red[1][wid] = ssp; red[2][wid] = dt; }
  __syncthreads();
  ssq = red[0][0] + red[0][1];
  ssp = red[1][0] + red[1][1];
  dt  = red[2][0] + red[2][1];
  const float invq = 1.0f / fmaxf(sqrtf(ssq), 1e-8f);
  const float invp = 1.0f / fmaxf(sqrtf(ssp), 1e-8f);
  int rq = 0, rp = 0;
  rq = __builtin_amdgcn_cvt_pk_fp8_f32(qv.x * invq, qv.y * invq, rq, false);
  rq = __builtin_amdgcn_cvt_pk_fp8_f32(qv.z * invq, qv.w * invq, rq, true);
  rp = __builtin_amdgcn_cvt_pk_fp8_f32(pv.x * invp, pv.y * invp, rp, false);
  rp = __builtin_amdgcn_cvt_pk_fp8_f32(pv.z * invp, pv.w * invp, rp, true);
  qh[i * 128 + t] = (unsigned int)rq;
  ph[i * 128 + t] = (unsigned int)rp;
  if (t == 0) diag[i] = dt * invq * invp * 20.0f;
}

// ---------- Phase 2: persistent MX-fp8 GEMM (scale=1), r7 schedule ----------
// 256 blocks (1/CU), 8 waves (2Mx4N), 128x64 out/wave, 4 output tiles/block,
// 4 K-tiles of 128 each -> 16 straight-line iterations. LDS 2 x 64KB dbuf
// (A 32KB + B 32KB per K-tile, XOR-swizzled, 2-way-free), + 4KB psum.
// MFMA: mfma_scale_f32_16x16x128_f8f6f4, scales = 0x7f7f7f7f (1.0) so opsel
// is irrelevant. Fragment: lane row = l&15, k = (l>>4)*32 + byte (32B/lane,
// two ds_read_b128 per frag, per-half swizzled addresses).
__device__ __forceinline__ i32x8 rd32(const char* base, int c0, int sw) {
  const i32x4 lo = *(const i32x4*)(base + ((c0     ) ^ sw));
  const i32x4 hi = *(const i32x4*)(base + ((c0 + 16) ^ sw));
  return __builtin_shufflevector(lo, hi, 0, 1, 2, 3, 4, 5, 6, 7);
}
__device__ __forceinline__ void stage_half(const char* __restrict__ g, char* dstb,
                                           int rowbase, int h, int tid, int kb) {
  #pragma unroll
  for (int j = 0; j < 2; ++j) {
    const int idx = j * 512 + tid;
    const int rl = idx >> 3;
    const int scb = ((idx & 7) << 4) ^ ((rl & 7) << 4);
    gld_lds16(g + (size_t)(rowbase + h * 128 + rl) * 512 + kb + scb,
              dstb + h * 16384 + idx * 16);
  }
}

#define MFMA_Q(AF, BF, Q, QB)                                                 \
  __builtin_amdgcn_s_setprio(1);                                              \
  _Pragma("unroll") for (int mf = 0; mf < 4; ++mf)                            \
    _Pragma("unroll") for (int nf = 0; nf < 2; ++nf)                          \
      acc[Q * 4 + mf][QB * 2 + nf] =                                          \
          __builtin_amdgcn_mfma_scale_f32_16x16x128_f8f6f4(                   \
              AF[mf], BF[nf], acc[Q * 4 + mf][QB * 2 + nf], 0, 0,             \
              0, FP8_SCALE_1, 0, FP8_SCALE_1);                                \
  __builtin_amdgcn_s_setprio(0);

__global__ __launch_bounds__(512, 2) void gemm_lse_k(
    const unsigned int* __restrict__ qh, const unsigned int* __restrict__ ph,
    float* __restrict__ partial) {
  __shared__ __attribute__((aligned(16))) char lds[135168];  // 2x64KB + 4KB psum
  const int tid = threadIdx.x;
  const int lane = tid & 63, wid = tid >> 6;
  const int wr = wid >> 2, wc = wid & 3;
  const int l15 = lane & 15, l4 = lane >> 4;
  const int sw = (l15 & 7) << 4;
  const int c0 = l4 * 32;
  const int b = blockIdx.x;
  const int bxg = b & 7;            // XCD id -> B column group
  const int by = b >> 3;            // 0..31
  const int bm = by * BM;
  const char* qh8 = (const char*)qh;
  const char* ph8 = (const char*)ph;
  float* psum = (float*)(lds + 131072);
  // per-wave LDS read bases (byte offsets added per fragment)
  const int aOff = wr * 16384 + l15 * 128;                         // + q*8192 + mf*2048
  const int bOff = 32768 + (wc >> 1) * 16384 +
                   ((wc & 1) * 64 + l15) * 128;                    // + qb*4096 + nf*2048

  f32x4 acc[8][4] = {};
  i32x8 af0[4], af1[4], bf0[2], bf1[2];

  // Prologue: stage tile 0 (output tile 0, k-tile 0), drain, barrier.
  {
    const int bn0 = bxg * 4 * BN;
    stage_half(qh8, lds, bm, 0, tid, 0);
    stage_half(ph8, lds + 32768, bn0, 0, tid, 0);
    stage_half(ph8, lds + 32768, bn0, 1, tid, 0);
    stage_half(qh8, lds, bm, 1, tid, 0);
    asm volatile("s_waitcnt vmcnt(0)" ::: "memory");
    __builtin_amdgcn_s_barrier();
  }

  #pragma unroll 1
  for (int tt = 0; tt < 16; ++tt) {
    const char* rb = lds + (tt & 1) * 65536;
    char* sbA = lds + ((tt + 1) & 1) * 65536;
    char* sbB = sbA + 32768;
    const int ttn = tt + 1;
    const int kbn = (ttn & 3) * 128;                     // next K-tile byte offset
    const int bnn = (bxg * 4 + ((ttn >> 2) & 3)) * BN;   // next tile's bn
    const bool st = (tt < 15);

    // front-load reads (16 + 8 ds_read_b128)
    #pragma unroll
    for (int mf = 0; mf < 4; ++mf)
      af0[mf] = rd32(rb + aOff + mf * 2048, c0, sw);
    #pragma unroll
    for (int nf = 0; nf < 2; ++nf)
      bf0[nf] = rd32(rb + bOff + nf * 2048, c0, sw);
    #pragma unroll
    for (int nf = 0; nf < 2; ++nf)
      bf1[nf] = rd32(rb + bOff + 4096 + nf * 2048, c0, sw);
    if (st) {
      stage_half(qh8, sbA, bm, 0, tid, kbn);
      stage_half(ph8, sbB, bnn, 0, tid, kbn);
    }
    MFMA_Q(af0, bf0, 0, 0);
    #pragma unroll
    for (int mf = 0; mf < 4; ++mf)
      af1[mf] = rd32(rb + aOff + 8192 + mf * 2048, c0, sw);
    MFMA_Q(af0, bf1, 0, 1);
    if (st) {
      stage_half(ph8, sbB, bnn, 1, tid, kbn);
      stage_half(qh8, sbA, bm, 1, tid, kbn);
    }
    MFMA_Q(af1, bf1, 1, 1);
    MFMA_Q(af1, bf0, 1, 0);

    asm volatile("s_waitcnt vmcnt(0)" ::: "memory");  // stages landed (issued early)
    __builtin_amdgcn_s_barrier();

    if ((tt & 3) == 3) {
      // ---- flush output tile (tt>>2): exp(20c-20) + row-sum + store ----
      const int bxc = bxg * 4 + (tt >> 2);
      #pragma unroll
      for (int am = 0; am < 8; ++am) {
        #pragma unroll
        for (int r = 0; r < 4; ++r) {
          float s = 0.0f;
          #pragma unroll
          for (int nb = 0; nb < 4; ++nb)
            s += __expf(acc[am][nb][r] * 20.0f - 20.0f);
          s += __shfl_xor(s, 1, 64);
          s += __shfl_xor(s, 2, 64);
          s += __shfl_xor(s, 4, 64);
          s += __shfl_xor(s, 8, 64);
          if (l15 == 0)
            psum[wc * 256 + wr * 128 + am * 16 + l4 * 4 + r] = s;
        }
      }
      asm volatile("s_waitcnt lgkmcnt(0)" ::: "memory");
      __builtin_amdgcn_s_barrier();
      if (tid < 256) {
        float s = psum[tid] + psum[256 + tid] + psum[512 + tid] + psum[768 + tid];
        partial[(size_t)(bm + tid) * 32 + bxc] = s;
      }
      #pragma unroll
      for (int am = 0; am < 8; ++am)
        #pragma unroll
        for (int nb = 0; nb < 4; ++nb)
          acc[am][nb] = f32x4{0.0f, 0.0f, 0.0f, 0.0f};
    }
  }
}

// ---------- Phase 3a: per-row loss ----------
__global__ __launch_bounds__(256) void rowloss_k(
    const float* __restrict__ partial, const float* __restrict__ diag,
    float* __restrict__ rowloss) {
  const int i = blockIdx.x * 256 + threadIdx.x;
  const float4* pr = (const float4*)(partial + (size_t)i * 32);
  float s = 0.0f;
  #pragma unroll
  for (int c = 0; c < 8; ++c) {
    const float4 v = pr[c];
    s += v.x + v.y + v.z + v.w;
  }
  rowloss[i] = __logf(s) + 20.0f - diag[i];
}

// ---------- Phase 3b: mean ----------
__global__ __launch_bounds__(1024) void final_k(
    const float* __restrict__ rowloss, float* __restrict__ out) {
  const int t = threadIdx.x;
  float s = 0.0f;
  #pragma unroll
  for (int j = 0; j < 8; ++j) s += rowloss[t + j * 1024];
  #pragma unroll
  for (int m = 1; m < 64; m <<= 1) s += __shfl_xor(s, m, 64);
  __shared__ float red[16];
  if ((t & 63) == 0) red[t >> 6] = s;
  __syncthreads();
  if (t == 0) {
    float acc = 0.0f;
    #pragma unroll
    for (int w = 0; w < 16; ++w) acc += red[w];
    out[0] = acc * (1.0f / (float)NROWS);
  }
}

extern "C" void kernel_launch(void* const* d_in, const int* in_sizes, int n_in,
                              void* d_out, int out_size, void* d_ws, size_t ws_size,
                              hipStream_t stream) {
  const float* q = (const float*)d_in[0];
  const float* p = (const float*)d_in[1];
  char* w = (char*)d_ws;
  unsigned int* qh = (unsigned int*)w;                        // 4 MB fp8
  unsigned int* ph = (unsigned int*)(w + 4194304);            // 4 MB fp8
  float* partial    = (float*)(w + 8388608);                  // 1 MB [8192][32]
  float* diag       = (float*)(w + 9437184);                  // 32 KB
  float* rowloss    = (float*)(w + 9437184 + 32768);          // 32 KB
  float* out = (float*)d_out;

  prep_k<<<NROWS, 128, 0, stream>>>(q, p, qh, ph, diag);
  gemm_lse_k<<<256, 512, 0, stream>>>(qh, ph, partial);
  rowloss_k<<<NROWS / 256, 256, 0, stream>>>(partial, diag, rowloss);
  final_k<<<1, 1024, 0, stream>>>(rowloss, out);
}